// Round 22
// baseline (192.735 us; speedup 1.0000x reference)
//
#include <hip/hip_runtime.h>
#include <math.h>

constexpr int NU = 100000;
constexpr int NI = 50000;
constexpr int NN = 150000;   // NU + NI
constexpr int D  = 64;
constexpr int NE = 1200000;
constexpr int NE4 = NE / 4;
constexpr int B  = 4096;
constexpr int CAPB = 64;     // max in-degree of a batch col   (Poisson(8): max ~35)
constexpr int CAP2 = 40;     // max in-degree of a marked col  (P(>=40) ~ 1e-10)

// LDS histogram geometry (row-hist and col-hist share it)
constexpr int NCHUNK = 3;
constexpr int CHUNK  = 65536;        // nodes per chunk (byte counters -> 64 KB LDS)
constexpr int CWORDS = CHUNK / 4;    // 16384 words
constexpr int WORDS  = 37504;        // padded word stride per slice copy (NN/4 = 37500)
constexpr int RWORDS = 37500;        // real words
constexpr int NSLICE = 80;
constexpr int SLICE4 = NE4 / NSLICE; // 3750 int4 per slice
constexpr int NHB    = NCHUNK * NSLICE;  // 240 row-hist blocks; +240 col-hist = 480

// scatter chunk geometry (smaller chunks -> more blocks -> better occupancy)
constexpr int CH2    = 6;
constexpr int CW2    = 6272;         // words per scatter chunk (25088 B LDS)
constexpr int CHUNK2 = CW2 * 4;      // 25088 nodes

constexpr int BMW = 4704;            // bitmap words (150016/32 = 4688, padded)

// workspace layout (int offsets):
//   bm1   @0        4704   [zeroed by k_flag]
//   cnt2d @4704     150016 [fully written by k_dinvc2 — no zeroing needed]
//   cntBd @154720   8448   [zeroed by k_flag]
//   ncnt  @163168   16     [zeroed by k_flag]
//   bm0   @163184   4704   [written in full by k_flag]
//   nb    @167888   16     [written by k_flag]
//   dinv  @167904   150016
//   bidx  @317920   150016
//   list  @467936   150016
//   csrBd @617952   540672 (8448*64)
//   csr2d @1158624  6000640 (150016*40)
//   embA  @7159264  9600000
//
// ALIASING (R17 lesson: no buffer may have an intra-kernel concurrent
// reader+writer): hcopy, hcopy2, base_pk all alias INSIDE embA
// (3.0M ints each, 9.0M <= 9.6M). Timeline:
//   k_hist2   WRITES hcopy+hcopy2 (embA dead)
//   k_dinvc2  READS  hcopy+hcopy2, WRITES base_pk (disjoint thirds of embA)
//   k_scatter READS  base_pk, WRITES csr2d (disjoint)
//   k_gather1 WRITES embA at listed rows (hist buffers dead)
//   k_score2  READS  embA only at marked(=listed) rows
//
// R19 LESSON (still applies): k_hist2's two branches BOTH use 64KB LDS, so
// there is no LDS-union tax; never fuse a big-LDS branch with a no-LDS
// occupancy-hungry branch.

// ---- single-block batch-node claim (LDS bitmap + counter); zeroes bm1/cntBd/ncnt ----
__global__ void __launch_bounds__(1024) k_flag(const int* __restrict__ users,
                                               const int* __restrict__ items,
                                               unsigned int* __restrict__ bm0,
                                               int* __restrict__ bidx,
                                               int* __restrict__ nb,
                                               unsigned int* __restrict__ bm1,
                                               int* __restrict__ cntBd,
                                               int* __restrict__ ncnt) {
    for (int i = threadIdx.x; i < BMW; i += 1024) bm1[i] = 0;
    for (int i = threadIdx.x; i < 8448; i += 1024) cntBd[i] = 0;
    if (threadIdx.x == 0) *ncnt = 0;

    __shared__ unsigned int sbm[BMW];
    __shared__ int snb;
    for (int i = threadIdx.x; i < BMW; i += 1024) sbm[i] = 0;
    if (threadIdx.x == 0) snb = 0;
    __syncthreads();
    for (int t = threadIdx.x; t < 2 * B; t += 1024) {
        const int node = (t < B) ? users[t] : items[t - B] + NU;
        const unsigned int old = atomicOr(&sbm[node >> 5], 1u << (node & 31));
        if (!((old >> (node & 31)) & 1)) bidx[node] = atomicAdd(&snb, 1);
    }
    __syncthreads();
    for (int i = threadIdx.x; i < BMW; i += 1024) bm0[i] = sbm[i];
    if (threadIdx.x == 0) *nb = snb;
}

// ---- fused row-hist (blocks 0..239) + col-hist (blocks 240..479), both via
//      64KB-LDS byte counters, zero global atomics. Col-hist was FREE: the
//      row-hist alone used only half the machine (2 blocks/CU x 120 CUs). ----
__global__ void __launch_bounds__(256) k_hist2(const int* __restrict__ row,
                                               const int* __restrict__ col,
                                               unsigned int* __restrict__ hcopy,
                                               unsigned int* __restrict__ hcopy2) {
    const bool isCol = (blockIdx.x >= NHB);
    const int  bid   = isCol ? (blockIdx.x - NHB) : blockIdx.x;
    const int* src   = isCol ? col : row;
    unsigned int* dstbase = isCol ? hcopy2 : hcopy;

    __shared__ unsigned int lh[CWORDS];
    const int ci = bid / NSLICE;
    const int si = bid % NSLICE;
    const int lo = ci * CHUNK;
    const int cw = (ci == NCHUNK - 1) ? (WORDS - (NCHUNK - 1) * CWORDS) : CWORDS;
    for (int w = threadIdx.x; w < cw; w += 256) lh[w] = 0;
    __syncthreads();
    const int4* r4 = reinterpret_cast<const int4*>(src) + (size_t)si * SLICE4;
    const unsigned int span = (unsigned)(cw * 4);
    for (int t = threadIdx.x; t < SLICE4; t += 256) {
        const int4 r = r4[t];
        int v;
        v = r.x - lo; if ((unsigned)v < span) atomicAdd(&lh[v >> 2], 1u << (8 * (v & 3)));
        v = r.y - lo; if ((unsigned)v < span) atomicAdd(&lh[v >> 2], 1u << (8 * (v & 3)));
        v = r.z - lo; if ((unsigned)v < span) atomicAdd(&lh[v >> 2], 1u << (8 * (v & 3)));
        v = r.w - lo; if ((unsigned)v < span) atomicAdd(&lh[v >> 2], 1u << (8 * (v & 3)));
    }
    __syncthreads();
    unsigned int* dst = dstbase + (size_t)si * WORDS + ci * CWORDS;
    for (int w = threadIdx.x; w < cw; w += 256) dst[w] = lh[w];
}

// ---- full edge pass: batch-col fixed-slot CSR fill + mark source rows (bm1);
//      no LDS -> full occupancy for atomic-latency hiding ----
__global__ void k_mark(const int* __restrict__ row, const int* __restrict__ col,
                       const unsigned int* __restrict__ bm0,
                       const int* __restrict__ bidx,
                       int* __restrict__ cntBd, int* __restrict__ csrBd,
                       unsigned int* __restrict__ bm1) {
    const int t = blockIdx.x * blockDim.x + threadIdx.x;
    if (t >= NE4) return;
    const int4 r = reinterpret_cast<const int4*>(row)[t];
    const int4 c = reinterpret_cast<const int4*>(col)[t];
    #define E1(rr, cc) if ((bm0[(cc) >> 5] >> ((cc) & 31)) & 1) { \
        const int bi = bidx[cc]; \
        const int s = atomicAdd(&cntBd[bi], 1); \
        csrBd[bi * CAPB + s] = rr; \
        atomicOr(&bm1[(rr) >> 5], 1u << ((rr) & 31)); }
    E1(r.x, c.x) E1(r.y, c.y) E1(r.z, c.z) E1(r.w, c.w)
    #undef E1
}

// ---- reduce: row-hist -> dinv ; col-hist -> exclusive slice-prefix (byte-
//      packed base_pk) + total -> cnt2d ; bm1-list compaction. One thread per
//      4-node word. base_pk writes are wave-coalesced (64 threads x 4B/slice). ----
__global__ void k_dinvc2(const unsigned int* __restrict__ hcopy,
                         const unsigned int* __restrict__ hcopy2,
                         float* __restrict__ dinv, int* __restrict__ cnt2d,
                         unsigned int* __restrict__ base_pk,
                         const unsigned int* __restrict__ bm1,
                         int* __restrict__ list, int* __restrict__ ncnt) {
    const int w = blockIdx.x * blockDim.x + threadIdx.x;
    if (w >= RWORDS) return;
    // row-degree reduce -> dinv (unchanged math/order)
    unsigned int s = 0;
    #pragma unroll 8
    for (int si = 0; si < NSLICE; ++si) s += hcopy[(size_t)si * WORDS + w];
    const int d0 = s & 255, d1 = (s >> 8) & 255, d2 = (s >> 16) & 255, d3 = (int)(s >> 24);
    float4 dv;
    dv.x = d0 > 0 ? 1.0f / sqrtf((float)d0) : 0.0f;
    dv.y = d1 > 0 ? 1.0f / sqrtf((float)d1) : 0.0f;
    dv.z = d2 > 0 ? 1.0f / sqrtf((float)d2) : 0.0f;
    dv.w = d3 > 0 ? 1.0f / sqrtf((float)d3) : 0.0f;
    reinterpret_cast<float4*>(dinv)[w] = dv;
    // col-degree exclusive prefix over slices (byte-packed, totals <= ~35 < 255)
    unsigned int run = 0;
    #pragma unroll 8
    for (int si = 0; si < NSLICE; ++si) {
        base_pk[(size_t)si * WORDS + w] = run;
        run += hcopy2[(size_t)si * WORDS + w];
    }
    int4 ct;
    ct.x = run & 255; ct.y = (run >> 8) & 255; ct.z = (run >> 16) & 255; ct.w = (int)(run >> 24);
    reinterpret_cast<int4*>(cnt2d)[w] = ct;       // full col-degree (= old cnt2d)
    // bm1 compaction
    const unsigned int bits = (bm1[w >> 3] >> ((w & 7) * 4)) & 0xFu;
    const int n0 = w * 4;
    if (bits & 1u) list[atomicAdd(ncnt, 1)] = n0;  // wave-aggregated by compiler
    if (bits & 2u) list[atomicAdd(ncnt, 1)] = n0 + 1;
    if (bits & 4u) list[atomicAdd(ncnt, 1)] = n0 + 2;
    if (bits & 8u) list[atomicAdd(ncnt, 1)] = n0 + 3;
}

// ---- counting-sort scatter: fill csr2d with ZERO global atomics.
//      slot = base_pk[slice][col] + LDS-byte-cursor++ . Unique: cursor within
//      slice, prefix across slices. 6 chunks x 80 slices, 25 KB LDS. ----
__global__ void __launch_bounds__(256) k_scatter(const int* __restrict__ row,
                                                 const int* __restrict__ col,
                                                 const unsigned int* __restrict__ bm1,
                                                 const unsigned int* __restrict__ base_pk,
                                                 int* __restrict__ csr2d) {
    __shared__ unsigned int lcur[CW2];
    const int ci = blockIdx.x / NSLICE;
    const int si = blockIdx.x % NSLICE;
    const int lo = ci * CHUNK2;
    const int cw = (ci == CH2 - 1) ? (WORDS - (CH2 - 1) * CW2) : CW2;
    for (int i = threadIdx.x; i < cw; i += 256) lcur[i] = 0;
    __syncthreads();
    const int4* r4 = reinterpret_cast<const int4*>(row) + (size_t)si * SLICE4;
    const int4* c4 = reinterpret_cast<const int4*>(col) + (size_t)si * SLICE4;
    const unsigned int span = (unsigned)(cw * 4);
    const unsigned int* bpk = base_pk + (size_t)si * WORDS;
    for (int t = threadIdx.x; t < SLICE4; t += 256) {
        const int4 r = r4[t];
        const int4 c = c4[t];
        #define E3(rr, cc) { const int v = (cc) - lo; \
            if ((unsigned)v < span && ((bm1[(cc) >> 5] >> ((cc) & 31)) & 1)) { \
                const unsigned int old = atomicAdd(&lcur[v >> 2], 1u << (8 * (v & 3))); \
                const int oldb = (old >> (8 * (v & 3))) & 255; \
                const int slot = (int)((bpk[(cc) >> 2] >> (8 * ((cc) & 3))) & 255) + oldb; \
                csr2d[(cc) * CAP2 + slot] = rr; } }
        E3(r.x, c.x) E3(r.y, c.y) E3(r.z, c.z) E3(r.w, c.w)
        #undef E3
    }
}

// ---- propagate 1, lazily: grid-stride, 4-deep gather ILP (measured optimum;
//      ~41 us random-row service floor — R11/R14 variants both regressed). ----
__global__ void k_gather1(const int* __restrict__ list, const int* __restrict__ ncnt,
                          const int* __restrict__ cnt2d, const int* __restrict__ csr2d,
                          const float* __restrict__ dinv,
                          const float* __restrict__ embU, const float* __restrict__ embI,
                          float* __restrict__ out) {
    const int lane = threadIdx.x & 63;
    const int n = *ncnt;
    const int nwv = gridDim.x * (blockDim.x >> 6);
    for (int idx = blockIdx.x * (blockDim.x >> 6) + (threadIdx.x >> 6);
         idx < n; idx += nwv) {
        const int c = list[idx];
        const int ne = cnt2d[c];
        const int* es = csr2d + (size_t)c * CAP2;
        float a0 = 0.0f, a1 = 0.0f, a2 = 0.0f, a3 = 0.0f;
        int e = 0;
        for (; e + 3 < ne; e += 4) {   // 4-deep ILP: int4 ids + 8 loads in flight
            const int4 r = *reinterpret_cast<const int4*>(es + e);   // 16B-aligned
            const float d0 = dinv[r.x], d1 = dinv[r.y], d2 = dinv[r.z], d3 = dinv[r.w];
            const float* s0 = (r.x < NU) ? embU + (size_t)r.x * D : embI + (size_t)(r.x - NU) * D;
            const float* s1 = (r.y < NU) ? embU + (size_t)r.y * D : embI + (size_t)(r.y - NU) * D;
            const float* s2 = (r.z < NU) ? embU + (size_t)r.z * D : embI + (size_t)(r.z - NU) * D;
            const float* s3 = (r.w < NU) ? embU + (size_t)r.w * D : embI + (size_t)(r.w - NU) * D;
            a0 = fmaf(d0, s0[lane], a0);
            a1 = fmaf(d1, s1[lane], a1);
            a2 = fmaf(d2, s2[lane], a2);
            a3 = fmaf(d3, s3[lane], a3);
        }
        for (; e < ne; ++e) {
            const int r = es[e];
            const float* s = (r < NU) ? embU + (size_t)r * D : embI + (size_t)(r - NU) * D;
            a0 = fmaf(dinv[r], s[lane], a0);
        }
        out[(size_t)c * D + lane] = dinv[c] * ((a0 + a1) + (a2 + a3));
    }
}

// ---- lazy in-place relu(x @ W.T + b) on listed rows only, LDS-free ----
__global__ void __launch_bounds__(256) k_mlp_relu(const int* __restrict__ list,
                                                  const int* __restrict__ ncnt,
                                                  float* __restrict__ emb,
                                                  const float* __restrict__ W,
                                                  const float* __restrict__ b) {
    const int lane = threadIdx.x & 63;
    float w[D];
    #pragma unroll
    for (int k4 = 0; k4 < D / 4; ++k4) {
        const float4 v = *reinterpret_cast<const float4*>(W + (size_t)lane * D + k4 * 4);
        w[k4 * 4 + 0] = v.x; w[k4 * 4 + 1] = v.y;
        w[k4 * 4 + 2] = v.z; w[k4 * 4 + 3] = v.w;
    }
    const float bias = b[lane];

    const int n = *ncnt;
    const int wid = blockIdx.x * (blockDim.x >> 6) + (threadIdx.x >> 6);
    const int nw  = gridDim.x * (blockDim.x >> 6);
    for (int i4 = wid * 4; i4 < n; i4 += nw * 4) {
        const int r0 = list[i4];
        const int r1 = (i4 + 1 < n) ? list[i4 + 1] : r0;   // tail: duplicate row0
        const int r2 = (i4 + 2 < n) ? list[i4 + 2] : r0;   // (same input -> same
        const int r3 = (i4 + 3 < n) ? list[i4 + 3] : r0;   //  result, write benign)
        float* x0 = emb + (size_t)r0 * D;
        float* x1 = emb + (size_t)r1 * D;
        float* x2 = emb + (size_t)r2 * D;
        float* x3 = emb + (size_t)r3 * D;
        const float xv0 = x0[lane], xv1 = x1[lane], xv2 = x2[lane], xv3 = x3[lane];
        float a0 = bias, a1 = bias, a2 = bias, a3 = bias;
        #pragma unroll
        for (int k = 0; k < D; ++k) {
            const float wk = w[k];
            a0 = fmaf(__int_as_float(__builtin_amdgcn_readlane(__float_as_int(xv0), k)), wk, a0);
            a1 = fmaf(__int_as_float(__builtin_amdgcn_readlane(__float_as_int(xv1), k)), wk, a1);
            a2 = fmaf(__int_as_float(__builtin_amdgcn_readlane(__float_as_int(xv2), k)), wk, a2);
            a3 = fmaf(__int_as_float(__builtin_amdgcn_readlane(__float_as_int(xv3), k)), wk, a3);
        }
        x0[lane] = fmaxf(a0, 0.0f);
        x1[lane] = fmaxf(a1, 0.0f);
        x2[lane] = fmaxf(a2, 0.0f);
        x3[lane] = fmaxf(a3, 0.0f);
    }
}

// ---- fused propagate2 + MLP2 + dot: one wave per (pair, node) ----
__global__ void __launch_bounds__(256) k_score2(const int* __restrict__ users,
                                                const int* __restrict__ items,
                                                const int* __restrict__ bidx,
                                                const int* __restrict__ cntBd,
                                                const int* __restrict__ csrBd,
                                                const float* __restrict__ dinv,
                                                const float* __restrict__ embA,
                                                const float* __restrict__ W,
                                                const float* __restrict__ b,
                                                float* __restrict__ out) {
    __shared__ float sy[2][2][D];        // [pair-in-block][t][lane]
    const int lane = threadIdx.x & 63;
    const int wid  = threadIdx.x >> 6;   // 0..3
    const int pp   = wid >> 1;           // pair slot in block
    const int t    = wid & 1;            // 0 = user node, 1 = item node
    const int p    = blockIdx.x * 2 + pp;    // grid = B/2 -> p < B always

    float w[D];                          // W2 row `lane` (L1-hot across waves)
    #pragma unroll
    for (int k4 = 0; k4 < D / 4; ++k4) {
        const float4 v = *reinterpret_cast<const float4*>(W + (size_t)lane * D + k4 * 4);
        w[k4 * 4 + 0] = v.x; w[k4 * 4 + 1] = v.y;
        w[k4 * 4 + 2] = v.z; w[k4 * 4 + 3] = v.w;
    }

    const int c  = (t == 0) ? users[p] : items[p] + NU;
    const int bi = bidx[c];
    const int n  = cntBd[bi];
    const int* es = csrBd + (size_t)bi * CAPB;
    float a0 = 0.0f, a1 = 0.0f, a2 = 0.0f, a3 = 0.0f;
    int e = 0;
    for (; e + 3 < n; e += 4) {          // 4-deep ILP (csrBd rows 256B-aligned)
        const int4 r = *reinterpret_cast<const int4*>(es + e);
        a0 = fmaf(dinv[r.x], embA[(size_t)r.x * D + lane], a0);
        a1 = fmaf(dinv[r.y], embA[(size_t)r.y * D + lane], a1);
        a2 = fmaf(dinv[r.z], embA[(size_t)r.z * D + lane], a2);
        a3 = fmaf(dinv[r.w], embA[(size_t)r.w * D + lane], a3);
    }
    for (; e < n; ++e) {
        const int r = es[e];
        a0 = fmaf(dinv[r], embA[(size_t)r * D + lane], a0);
    }
    const float x = dinv[c] * ((a0 + a1) + (a2 + a3));   // prop-2 value at lane

    float y = b[lane];
    #pragma unroll
    for (int k = 0; k < D; ++k)
        y = fmaf(__int_as_float(__builtin_amdgcn_readlane(__float_as_int(x), k)),
                 w[k], y);
    sy[pp][t][lane] = y;
    __syncthreads();
    if (t == 0) {
        float prod = sy[pp][0][lane] * sy[pp][1][lane];
        #pragma unroll
        for (int off = 32; off >= 1; off >>= 1) prod += __shfl_down(prod, off, 64);
        if (lane == 0) out[p] = prod;
    }
}

extern "C" void kernel_launch(void* const* d_in, const int* in_sizes, int n_in,
                              void* d_out, int out_size, void* d_ws, size_t ws_size,
                              hipStream_t stream) {
    const int*   users    = (const int*)d_in[0];
    const int*   items    = (const int*)d_in[1];
    const int*   edge     = (const int*)d_in[2];   // [2][NE]
    const float* user_emb = (const float*)d_in[3];
    const float* item_emb = (const float*)d_in[4];
    const float* W1       = (const float*)d_in[5];
    const float* b1       = (const float*)d_in[6];
    const float* W2       = (const float*)d_in[7];
    const float* b2       = (const float*)d_in[8];
    float*       out      = (float*)d_out;

    const int* row  = edge;
    const int* colp = edge + NE;

    unsigned int* bm1   = (unsigned int*)d_ws;            // @0        4704
    int*   cnt2d = (int*)d_ws + 4704;           //           150016 (fully written)
    int*   cntBd = (int*)d_ws + 154720;         //           8448
    int*   ncnt  = (int*)d_ws + 163168;         //           16
    unsigned int* bm0   = (unsigned int*)d_ws + 163184;   //  4704
    int*   nb    = (int*)d_ws + 167888;         //           16
    float* dinv  = (float*)d_ws + 167904;       //           150016
    int*   bidx  = (int*)d_ws + 317920;         //           150016
    int*   list  = (int*)d_ws + 467936;         //           150016
    int*   csrBd = (int*)d_ws + 617952;         //           540672 (8448*64)
    int*   csr2d = (int*)d_ws + 1158624;        //           6000640 (150016*40)
    float* embA  = (float*)d_ws + 7159264;      //           9600000
    // hist/prefix buffers live inside embA (3.0M ints each; embA dead until gather1)
    unsigned int* hcopy   = (unsigned int*)embA;                 // row-hist copies
    unsigned int* hcopy2  = (unsigned int*)embA + 3000320;       // col-hist copies
    unsigned int* base_pk = (unsigned int*)embA + 6000640;       // byte-packed prefixes

    // 1: batch claim + zero small counters
    k_flag <<<1, 1024, 0, stream>>>(users, items, bm0, bidx, nb, bm1, cntBd, ncnt);
    // 2: row-hist || col-hist (480 blocks, both 64KB-LDS branches, full machine)
    k_hist2<<<2 * NHB, 256, 0, stream>>>(row, colp, hcopy, hcopy2);
    // 3: batch CSR fill + source marking (no LDS, full occupancy)
    k_mark <<<(NE4 + 255) / 256, 256, 0, stream>>>(row, colp, bm0, bidx, cntBd, csrBd, bm1);
    // 4: reduce -> dinv, cnt2d, base_pk prefixes ; compact bm1 list
    k_dinvc2<<<(RWORDS + 255) / 256, 256, 0, stream>>>(hcopy, hcopy2, dinv, cnt2d,
                                                       base_pk, bm1, list, ncnt);
    // 5: counting-sort scatter into csr2d (zero global atomics)
    k_scatter<<<CH2 * NSLICE, 256, 0, stream>>>(row, colp, bm1, base_pk, csr2d);
    // 6: lazy propagate-1 (grid-stride, 4-deep ILP)
    k_gather1 <<<8192, 256, 0, stream>>>(list, ncnt, cnt2d, csr2d, dinv,
                                         user_emb, item_emb, embA);
    // 7: MLP1 on listed rows
    k_mlp_relu<<<2048, 256, 0, stream>>>(list, ncnt, embA, W1, b1);
    // 8: fused propagate-2 + MLP2 + dot
    k_score2<<<B / 2, 256, 0, stream>>>(users, items, bidx, cntBd, csrBd, dinv, embA,
                                        W2, b2, out);
}

// Round 26
// 157.389 us; speedup vs baseline: 1.2246x; 1.2246x over previous
//
#include <hip/hip_runtime.h>
#include <math.h>

constexpr int NU = 100000;
constexpr int NI = 50000;
constexpr int NN = 150000;   // NU + NI
constexpr int D  = 64;
constexpr int NE = 1200000;
constexpr int NE4 = NE / 4;
constexpr int B  = 4096;
constexpr int CAPB = 64;     // max in-degree of a batch col   (Poisson(8): max ~35)
constexpr int CAP2 = 40;     // max in-degree of a marked col  (P(>=40) ~ 1e-10)

// LDS degree histogram geometry
constexpr int NCHUNK = 3;
constexpr int CHUNK  = 65536;        // nodes per chunk (byte counters -> 64 KB LDS)
constexpr int CWORDS = CHUNK / 4;    // 16384 words
constexpr int WORDS  = 37504;        // padded word stride per slice copy (NN/4 = 37500)
constexpr int RWORDS = 37500;        // real words
constexpr int NSLICE = 80;
constexpr int SLICE4 = NE4 / NSLICE; // 3750 int4 per slice

constexpr int BMW = 4704;            // bitmap words (150016/32 = 4688, padded)
constexpr int CZ4 = 150016 / 4;      // cnt2d zero region, int4 count
constexpr int P2B = (NE + 255) / 256;    // pass2 blocks (1 edge/thread) = 4688

// workspace layout (int offsets):
//   bm1   @0        4704   [zeroed by k_flag]
//   cnt2d @4704     150016 [zeroed by k_hist prologue]
//   cntBd @154720   8448   [zeroed by k_flag]
//   ncnt  @163168   16     [zeroed by k_flag]
//   bm0   @163184   4704   [written in full by k_flag]
//   nb    @167888   16     [written by k_flag]
//   dinv  @167904   150016
//   bidx  @317920   150016
//   list  @467936   150016
//   csrBd @617952   540672 (8448*64)
//   csr2d @1158624  6000640 (150016*40)
//   embA  @7159264  9600000
//
// ALIASING: hcopy aliases embA (NOT csr2d — R17 bug). Timeline: k_hist writes
// hcopy(=embA, dead); k_pass2d reads hcopy || writes csr2d (disjoint);
// k_gather1 overwrites embA at listed rows; k_score2 reads only marked rows.
//
// R19 LESSON: never fuse a big-LDS branch with a no-LDS occupancy-hungry one.
// R22 LESSON: counting-sort scatter (zero atomics, 480 blocks) lost to the
// atomic version — removing atomics is worthless if the replacement starves
// wave parallelism (15% occupancy, 6x redundant edge reads). Keep atomics,
// maximize waves-in-flight instead.

// ---- single-block batch-node claim (LDS bitmap + counter); zeroes bm1/cntBd/ncnt ----
__global__ void __launch_bounds__(1024) k_flag(const int* __restrict__ users,
                                               const int* __restrict__ items,
                                               unsigned int* __restrict__ bm0,
                                               int* __restrict__ bidx,
                                               int* __restrict__ nb,
                                               unsigned int* __restrict__ bm1,
                                               int* __restrict__ cntBd,
                                               int* __restrict__ ncnt) {
    for (int i = threadIdx.x; i < BMW; i += 1024) bm1[i] = 0;
    for (int i = threadIdx.x; i < 8448; i += 1024) cntBd[i] = 0;
    if (threadIdx.x == 0) *ncnt = 0;

    __shared__ unsigned int sbm[BMW];
    __shared__ int snb;
    for (int i = threadIdx.x; i < BMW; i += 1024) sbm[i] = 0;
    if (threadIdx.x == 0) snb = 0;
    __syncthreads();
    for (int t = threadIdx.x; t < 2 * B; t += 1024) {
        const int node = (t < B) ? users[t] : items[t - B] + NU;
        const unsigned int old = atomicOr(&sbm[node >> 5], 1u << (node & 31));
        if (!((old >> (node & 31)) & 1)) bidx[node] = atomicAdd(&snb, 1);
    }
    __syncthreads();
    for (int i = threadIdx.x; i < BMW; i += 1024) bm0[i] = sbm[i];
    if (threadIdx.x == 0) *nb = snb;
}

// ---- degree histogram (LDS byte counters, zero global atomics), standalone;
//      prologue zeroes cnt2d ----
__global__ void __launch_bounds__(256) k_hist(const int* __restrict__ row,
                                              unsigned int* __restrict__ hcopy,
                                              int4* __restrict__ cnt2dz) {
    for (int i = blockIdx.x * 256 + threadIdx.x; i < CZ4; i += gridDim.x * 256)
        cnt2dz[i] = make_int4(0, 0, 0, 0);

    __shared__ unsigned int lh[CWORDS];
    const int ci = blockIdx.x / NSLICE;
    const int si = blockIdx.x % NSLICE;
    const int lo = ci * CHUNK;
    const int cw = (ci == NCHUNK - 1) ? (WORDS - (NCHUNK - 1) * CWORDS) : CWORDS;
    for (int w = threadIdx.x; w < cw; w += 256) lh[w] = 0;
    __syncthreads();
    const int4* r4 = reinterpret_cast<const int4*>(row) + (size_t)si * SLICE4;
    const unsigned int span = (unsigned)(cw * 4);
    for (int t = threadIdx.x; t < SLICE4; t += 256) {
        const int4 r = r4[t];
        int v;
        v = r.x - lo; if ((unsigned)v < span) atomicAdd(&lh[v >> 2], 1u << (8 * (v & 3)));
        v = r.y - lo; if ((unsigned)v < span) atomicAdd(&lh[v >> 2], 1u << (8 * (v & 3)));
        v = r.z - lo; if ((unsigned)v < span) atomicAdd(&lh[v >> 2], 1u << (8 * (v & 3)));
        v = r.w - lo; if ((unsigned)v < span) atomicAdd(&lh[v >> 2], 1u << (8 * (v & 3)));
    }
    __syncthreads();
    unsigned int* dst = hcopy + (size_t)si * WORDS + ci * CWORDS;
    for (int w = threadIdx.x; w < cw; w += 256) dst[w] = lh[w];
}

// ---- full edge pass: batch-col fixed-slot CSR fill + mark source rows (bm1);
//      no LDS -> full occupancy for atomic-latency hiding ----
__global__ void k_mark(const int* __restrict__ row, const int* __restrict__ col,
                       const unsigned int* __restrict__ bm0,
                       const int* __restrict__ bidx,
                       int* __restrict__ cntBd, int* __restrict__ csrBd,
                       unsigned int* __restrict__ bm1) {
    const int t = blockIdx.x * blockDim.x + threadIdx.x;
    if (t >= NE4) return;
    const int4 r = reinterpret_cast<const int4*>(row)[t];
    const int4 c = reinterpret_cast<const int4*>(col)[t];
    #define E1(rr, cc) if ((bm0[(cc) >> 5] >> ((cc) & 31)) & 1) { \
        const int bi = bidx[cc]; \
        const int s = atomicAdd(&cntBd[bi], 1); \
        csrBd[bi * CAPB + s] = rr; \
        atomicOr(&bm1[(rr) >> 5], 1u << ((rr) & 31)); }
    E1(r.x, c.x) E1(r.y, c.y) E1(r.z, c.z) E1(r.w, c.w)
    #undef E1
}

// ---- fused: dinv reduce + bm1-list compaction (blocks 0..146) CONCURRENT with
//      gather-CSR fill (blocks 147.., ONE edge per thread: 4x more waves than
//      R20's int4 version -> more independent RMW chains in flight). ----
__global__ void __launch_bounds__(256) k_pass2d(const int* __restrict__ row,
                                                const int* __restrict__ col,
                                                const unsigned int* __restrict__ bm1,
                                                int* __restrict__ cnt2d,
                                                int* __restrict__ csr2d,
                                                const unsigned int* __restrict__ hcopy,
                                                float* __restrict__ dinv,
                                                int* __restrict__ list,
                                                int* __restrict__ ncnt) {
    if (blockIdx.x < 147) {
        // ---- dinvc part ----
        const int w = blockIdx.x * 256 + threadIdx.x;
        if (w >= RWORDS) return;
        unsigned int s = 0;
        #pragma unroll 8
        for (int si = 0; si < NSLICE; ++si) s += hcopy[(size_t)si * WORDS + w];
        const int d0 = s & 255, d1 = (s >> 8) & 255, d2 = (s >> 16) & 255, d3 = (int)(s >> 24);
        float4 dv;
        dv.x = d0 > 0 ? 1.0f / sqrtf((float)d0) : 0.0f;
        dv.y = d1 > 0 ? 1.0f / sqrtf((float)d1) : 0.0f;
        dv.z = d2 > 0 ? 1.0f / sqrtf((float)d2) : 0.0f;
        dv.w = d3 > 0 ? 1.0f / sqrtf((float)d3) : 0.0f;
        reinterpret_cast<float4*>(dinv)[w] = dv;
        const unsigned int bits = (bm1[w >> 3] >> ((w & 7) * 4)) & 0xFu;  // 4 nodes
        const int n0 = w * 4;
        if (bits & 1u) list[atomicAdd(ncnt, 1)] = n0;  // wave-aggregated by compiler
        if (bits & 2u) list[atomicAdd(ncnt, 1)] = n0 + 1;
        if (bits & 4u) list[atomicAdd(ncnt, 1)] = n0 + 2;
        if (bits & 8u) list[atomicAdd(ncnt, 1)] = n0 + 3;
    } else {
        // ---- pass2 part: gather-CSR fill for bm1 cols, 1 edge/thread ----
        const int t = (blockIdx.x - 147) * 256 + threadIdx.x;
        if (t >= NE) return;
        const int rr = row[t];
        const int cc = col[t];
        if ((bm1[cc >> 5] >> (cc & 31)) & 1) {
            const int s = atomicAdd(&cnt2d[cc], 1);
            csr2d[cc * CAP2 + s] = rr;
        }
    }
}

// ---- propagate 1, lazily: grid-stride, 4-deep gather ILP (measured optimum;
//      ~41 us random-row service floor — R11/R14 variants both regressed). ----
__global__ void k_gather1(const int* __restrict__ list, const int* __restrict__ ncnt,
                          const int* __restrict__ cnt2d, const int* __restrict__ csr2d,
                          const float* __restrict__ dinv,
                          const float* __restrict__ embU, const float* __restrict__ embI,
                          float* __restrict__ out) {
    const int lane = threadIdx.x & 63;
    const int n = *ncnt;
    const int nwv = gridDim.x * (blockDim.x >> 6);
    for (int idx = blockIdx.x * (blockDim.x >> 6) + (threadIdx.x >> 6);
         idx < n; idx += nwv) {
        const int c = list[idx];
        const int ne = cnt2d[c];
        const int* es = csr2d + (size_t)c * CAP2;
        float a0 = 0.0f, a1 = 0.0f, a2 = 0.0f, a3 = 0.0f;
        int e = 0;
        for (; e + 3 < ne; e += 4) {   // 4-deep ILP: int4 ids + 8 loads in flight
            const int4 r = *reinterpret_cast<const int4*>(es + e);   // 16B-aligned
            const float d0 = dinv[r.x], d1 = dinv[r.y], d2 = dinv[r.z], d3 = dinv[r.w];
            const float* s0 = (r.x < NU) ? embU + (size_t)r.x * D : embI + (size_t)(r.x - NU) * D;
            const float* s1 = (r.y < NU) ? embU + (size_t)r.y * D : embI + (size_t)(r.y - NU) * D;
            const float* s2 = (r.z < NU) ? embU + (size_t)r.z * D : embI + (size_t)(r.z - NU) * D;
            const float* s3 = (r.w < NU) ? embU + (size_t)r.w * D : embI + (size_t)(r.w - NU) * D;
            a0 = fmaf(d0, s0[lane], a0);
            a1 = fmaf(d1, s1[lane], a1);
            a2 = fmaf(d2, s2[lane], a2);
            a3 = fmaf(d3, s3[lane], a3);
        }
        for (; e < ne; ++e) {
            const int r = es[e];
            const float* s = (r < NU) ? embU + (size_t)r * D : embI + (size_t)(r - NU) * D;
            a0 = fmaf(dinv[r], s[lane], a0);
        }
        out[(size_t)c * D + lane] = dinv[c] * ((a0 + a1) + (a2 + a3));
    }
}

// ---- lazy in-place relu(x @ W.T + b) on listed rows only, LDS-free ----
__global__ void __launch_bounds__(256) k_mlp_relu(const int* __restrict__ list,
                                                  const int* __restrict__ ncnt,
                                                  float* __restrict__ emb,
                                                  const float* __restrict__ W,
                                                  const float* __restrict__ b) {
    const int lane = threadIdx.x & 63;
    float w[D];
    #pragma unroll
    for (int k4 = 0; k4 < D / 4; ++k4) {
        const float4 v = *reinterpret_cast<const float4*>(W + (size_t)lane * D + k4 * 4);
        w[k4 * 4 + 0] = v.x; w[k4 * 4 + 1] = v.y;
        w[k4 * 4 + 2] = v.z; w[k4 * 4 + 3] = v.w;
    }
    const float bias = b[lane];

    const int n = *ncnt;
    const int wid = blockIdx.x * (blockDim.x >> 6) + (threadIdx.x >> 6);
    const int nw  = gridDim.x * (blockDim.x >> 6);
    for (int i4 = wid * 4; i4 < n; i4 += nw * 4) {
        const int r0 = list[i4];
        const int r1 = (i4 + 1 < n) ? list[i4 + 1] : r0;   // tail: duplicate row0
        const int r2 = (i4 + 2 < n) ? list[i4 + 2] : r0;   // (same input -> same
        const int r3 = (i4 + 3 < n) ? list[i4 + 3] : r0;   //  result, write benign)
        float* x0 = emb + (size_t)r0 * D;
        float* x1 = emb + (size_t)r1 * D;
        float* x2 = emb + (size_t)r2 * D;
        float* x3 = emb + (size_t)r3 * D;
        const float xv0 = x0[lane], xv1 = x1[lane], xv2 = x2[lane], xv3 = x3[lane];
        float a0 = bias, a1 = bias, a2 = bias, a3 = bias;
        #pragma unroll
        for (int k = 0; k < D; ++k) {
            const float wk = w[k];
            a0 = fmaf(__int_as_float(__builtin_amdgcn_readlane(__float_as_int(xv0), k)), wk, a0);
            a1 = fmaf(__int_as_float(__builtin_amdgcn_readlane(__float_as_int(xv1), k)), wk, a1);
            a2 = fmaf(__int_as_float(__builtin_amdgcn_readlane(__float_as_int(xv2), k)), wk, a2);
            a3 = fmaf(__int_as_float(__builtin_amdgcn_readlane(__float_as_int(xv3), k)), wk, a3);
        }
        x0[lane] = fmaxf(a0, 0.0f);
        x1[lane] = fmaxf(a1, 0.0f);
        x2[lane] = fmaxf(a2, 0.0f);
        x3[lane] = fmaxf(a3, 0.0f);
    }
}

// ---- fused propagate2 + MLP2 + dot: one wave per (pair, node) ----
__global__ void __launch_bounds__(256) k_score2(const int* __restrict__ users,
                                                const int* __restrict__ items,
                                                const int* __restrict__ bidx,
                                                const int* __restrict__ cntBd,
                                                const int* __restrict__ csrBd,
                                                const float* __restrict__ dinv,
                                                const float* __restrict__ embA,
                                                const float* __restrict__ W,
                                                const float* __restrict__ b,
                                                float* __restrict__ out) {
    __shared__ float sy[2][2][D];        // [pair-in-block][t][lane]
    const int lane = threadIdx.x & 63;
    const int wid  = threadIdx.x >> 6;   // 0..3
    const int pp   = wid >> 1;           // pair slot in block
    const int t    = wid & 1;            // 0 = user node, 1 = item node
    const int p    = blockIdx.x * 2 + pp;    // grid = B/2 -> p < B always

    float w[D];                          // W2 row `lane` (L1-hot across waves)
    #pragma unroll
    for (int k4 = 0; k4 < D / 4; ++k4) {
        const float4 v = *reinterpret_cast<const float4*>(W + (size_t)lane * D + k4 * 4);
        w[k4 * 4 + 0] = v.x; w[k4 * 4 + 1] = v.y;
        w[k4 * 4 + 2] = v.z; w[k4 * 4 + 3] = v.w;
    }

    const int c  = (t == 0) ? users[p] : items[p] + NU;
    const int bi = bidx[c];
    const int n  = cntBd[bi];
    const int* es = csrBd + (size_t)bi * CAPB;
    float a0 = 0.0f, a1 = 0.0f, a2 = 0.0f, a3 = 0.0f;
    int e = 0;
    for (; e + 3 < n; e += 4) {          // 4-deep ILP (csrBd rows 256B-aligned)
        const int4 r = *reinterpret_cast<const int4*>(es + e);
        a0 = fmaf(dinv[r.x], embA[(size_t)r.x * D + lane], a0);
        a1 = fmaf(dinv[r.y], embA[(size_t)r.y * D + lane], a1);
        a2 = fmaf(dinv[r.z], embA[(size_t)r.z * D + lane], a2);
        a3 = fmaf(dinv[r.w], embA[(size_t)r.w * D + lane], a3);
    }
    for (; e < n; ++e) {
        const int r = es[e];
        a0 = fmaf(dinv[r], embA[(size_t)r * D + lane], a0);
    }
    const float x = dinv[c] * ((a0 + a1) + (a2 + a3));   // prop-2 value at lane

    float y = b[lane];
    #pragma unroll
    for (int k = 0; k < D; ++k)
        y = fmaf(__int_as_float(__builtin_amdgcn_readlane(__float_as_int(x), k)),
                 w[k], y);
    sy[pp][t][lane] = y;
    __syncthreads();
    if (t == 0) {
        float prod = sy[pp][0][lane] * sy[pp][1][lane];
        #pragma unroll
        for (int off = 32; off >= 1; off >>= 1) prod += __shfl_down(prod, off, 64);
        if (lane == 0) out[p] = prod;
    }
}

extern "C" void kernel_launch(void* const* d_in, const int* in_sizes, int n_in,
                              void* d_out, int out_size, void* d_ws, size_t ws_size,
                              hipStream_t stream) {
    const int*   users    = (const int*)d_in[0];
    const int*   items    = (const int*)d_in[1];
    const int*   edge     = (const int*)d_in[2];   // [2][NE]
    const float* user_emb = (const float*)d_in[3];
    const float* item_emb = (const float*)d_in[4];
    const float* W1       = (const float*)d_in[5];
    const float* b1       = (const float*)d_in[6];
    const float* W2       = (const float*)d_in[7];
    const float* b2       = (const float*)d_in[8];
    float*       out      = (float*)d_out;

    const int* row  = edge;
    const int* colp = edge + NE;

    unsigned int* bm1   = (unsigned int*)d_ws;            // @0        4704
    int*   cnt2d = (int*)d_ws + 4704;           //           150016
    int*   cntBd = (int*)d_ws + 154720;         //           8448
    int*   ncnt  = (int*)d_ws + 163168;         //           16
    unsigned int* bm0   = (unsigned int*)d_ws + 163184;   //  4704
    int*   nb    = (int*)d_ws + 167888;         //           16
    float* dinv  = (float*)d_ws + 167904;       //           150016
    int*   bidx  = (int*)d_ws + 317920;         //           150016
    int*   list  = (int*)d_ws + 467936;         //           150016
    int*   csrBd = (int*)d_ws + 617952;         //           540672 (8448*64)
    int*   csr2d = (int*)d_ws + 1158624;        //           6000640 (150016*40)
    float* embA  = (float*)d_ws + 7159264;      //           9600000
    // hcopy aliases embA (NOT csr2d): written by k_hist, read by k_pass2d
    // (while csr2d is written — disjoint), overwritten by k_gather1 at listed rows.
    unsigned int* hcopy = (unsigned int*)embA;

    // 1: batch claim + zero small counters
    k_flag <<<1, 1024, 0, stream>>>(users, items, bm0, bidx, nb, bm1, cntBd, ncnt);
    // 2: degree histogram (standalone 64KB-LDS kernel) + cnt2d zero prologue
    k_hist <<<NCHUNK * NSLICE, 256, 0, stream>>>(row, hcopy, (int4*)cnt2d);
    // 3: batch CSR fill + source marking (no LDS, full occupancy)
    k_mark <<<(NE4 + 255) / 256, 256, 0, stream>>>(row, colp, bm0, bidx, cntBd, csrBd, bm1);
    // 4: dinv+compact (147 blocks) || gather-CSR fill (4688 blocks, 1 edge/thread)
    k_pass2d<<<147 + P2B, 256, 0, stream>>>(row, colp, bm1, cnt2d, csr2d,
                                            hcopy, dinv, list, ncnt);
    // 5: lazy propagate-1 (grid-stride, 4-deep ILP)
    k_gather1 <<<8192, 256, 0, stream>>>(list, ncnt, cnt2d, csr2d, dinv,
                                         user_emb, item_emb, embA);
    // 6: MLP1 on listed rows
    k_mlp_relu<<<2048, 256, 0, stream>>>(list, ncnt, embA, W1, b1);
    // 7: fused propagate-2 + MLP2 + dot
    k_score2<<<B / 2, 256, 0, stream>>>(users, items, bidx, cntBd, csrBd, dinv, embA,
                                        W2, b2, out);
}